// Round 3
// baseline (267.748 us; speedup 1.0000x reference)
//
#include <hip/hip_runtime.h>
#include <cstdint>

// BinConv2dEval: y = conv3x3(x,W) + bias; out = (sign*y >= 0) ? 1 : 0
// x: [32][128][64][64] fp32 in {0,1};  W: [256][128][3][3] fp32 in {-1,0,1}
// bias: [256] integer-valued fp32; sign: [256] in {-1,+1}; out fp32 NCHW.
//
// Strategy: all-integer implicit GEMM with i8 MFMA (16x16x64).
//  ws layout: xt = i8 NHWC zero-padded [32][66][66][128]  (17,842,176 B)
//             wp = i8 [tap(9)][co(256)][ci(128)]          (  294,912 B)
// R2: barrier-free GEMM K-loop (X staged once/block, W direct from L2).
// R3: XOR-swizzle xt chunk layout — chunk c of pixel px stored at c^(px&7)
//     — kills the 16-way LDS bank conflict (row stride 128 B = 32 banks).

#define NIMG 32
#define CIN  128
#define HH   64
#define WW   64
#define COUT 256
#define PH   66                       // padded spatial
#define XT_ROWSTRIDE (PH * CIN)       // 8448 bytes per padded row
#define XT_NSTRIDE   (PH * PH * CIN)  // 557568 bytes per image
#define XT_BYTES     ((size_t)NIMG * XT_NSTRIDE)
#define WP_TAPSTRIDE (COUT * CIN)     // 32768
#define WP_BYTES     ((size_t)9 * WP_TAPSTRIDE)

typedef int v4i __attribute__((ext_vector_type(4)));

// -------------------------------------------------------------------------
// Prepass: x fp32 NCHW -> i8 NHWC (chunk-swizzled), zero-padded borders.
// One block per (padded row py, image n). LDS transpose [64 x][144 ci].
// Swizzle: within each pixel's 128-B ci block, 16-B chunk c lands at
// position c ^ (px & 7). Zeros (pad) are swizzle-invariant.
__global__ __launch_bounds__(256) void xt_prepass(const float* __restrict__ x,
                                                  int8_t* __restrict__ xt) {
    const int py = blockIdx.x;   // 0..65
    const int n  = blockIdx.y;   // 0..31
    const int t  = threadIdx.x;
    int8_t* rowbase = xt + (size_t)(n * PH + py) * XT_ROWSTRIDE;

    if (py == 0 || py == PH - 1) {          // pure pad row: zeros
        int4 z = {0, 0, 0, 0};
        for (int j = t; j < XT_ROWSTRIDE / 16; j += 256)
            ((int4*)rowbase)[j] = z;
        return;
    }

    __shared__ __align__(16) int8_t Ls[64 * 144];  // [x][ci], +16B row pad
    const int y  = py - 1;
    const int xq = t & 15;                  // float4 index along x
    const float4* xf = (const float4*)x;
#pragma unroll
    for (int j = 0; j < 8; ++j) {
        const int ci = (t >> 4) + j * 16;   // 0..127
        float4 v = xf[((size_t)(n * CIN + ci) * HH + y) * 16 + xq];
        const int xv = xq * 4;
        Ls[(xv + 0) * 144 + ci] = (int8_t)v.x;
        Ls[(xv + 1) * 144 + ci] = (int8_t)v.y;
        Ls[(xv + 2) * 144 + ci] = (int8_t)v.z;
        Ls[(xv + 3) * 144 + ci] = (int8_t)v.w;
    }
    __syncthreads();
    const int4 z = {0, 0, 0, 0};
    for (int j = t; j < XT_ROWSTRIDE / 16; j += 256) {   // 528 int4 chunks
        const int px  = j >> 3;             // 0..65
        const int c   = j & 7;              // source chunk within pixel
        int4 val;
        if (px == 0 || px == PH - 1) val = z;
        else                         val = *(const int4*)&Ls[(px - 1) * 144 + c * 16];
        // swizzled destination: chunk c -> position c ^ (px&7)
        *(int4*)(rowbase + (size_t)px * CIN + ((c ^ (px & 7)) << 4)) = val;
    }
}

// -------------------------------------------------------------------------
// Weight prepack: OIHW fp32 -> i8 [tap][co][ci]
__global__ __launch_bounds__(256) void w_prepack(const float* __restrict__ w,
                                                 int8_t* __restrict__ wp) {
    const int idx = blockIdx.x * 256 + threadIdx.x;   // 0..294911
    if (idx >= (int)WP_BYTES) return;
    const int tap = idx >> 15;          // /32768
    const int rem = idx & 32767;
    const int co  = rem >> 7;
    const int ci  = rem & 127;
    wp[idx] = (int8_t)w[(size_t)(co * CIN + ci) * 9 + tap];
}

// -------------------------------------------------------------------------
// async global->LDS, 16B/lane. LDS dest = m0 (wave-uniform) + lane*16.
__device__ __forceinline__ void glds16(const void* g, uint32_t lds_off) {
    asm volatile("s_mov_b32 m0, %0\n"
                 "global_load_lds_dwordx4 %1, off"
                 :: "s"(lds_off), "v"(g) : "memory");
}

// -------------------------------------------------------------------------
// Main GEMM: D[co][m] = sum_taps W_tap[co][ci] * X_tap[ci][m]
// block: 128co x 128m (2 output rows x 64 cols), 4 waves, each 64co x 64m.
// X: 4 contiguous padded xt rows staged ONCE into LDS (33,792 B, swizzled);
//    every (tap,half) B-fragment is an immediate ds_read_b128, 2-way free.
// W: A-fragments read directly from global wp (288 KB, L2-hot).
// NO barriers in the K-loop.
__global__ __launch_bounds__(256) void binconv_gemm(
    const int8_t* __restrict__ xt, const int8_t* __restrict__ wp,
    const float* __restrict__ bias, const float* __restrict__ sign,
    float* __restrict__ out) {

    __shared__ __align__(16) int8_t Xraw[4 * XT_ROWSTRIDE];  // 33,792 B

    const int t    = threadIdx.x;
    const int wid  = t >> 6;
    const int lane = t & 63;
    const int bx   = blockIdx.x;            // 1024 m-blocks
    const int co0  = blockIdx.y * 128;      // 0 / 128
    const int n    = bx >> 5;
    const int y0   = (bx & 31) << 1;        // 2 output rows per block

    // ---- stage 4 padded rows (33 KiB) verbatim, once ----
    const int8_t* xbase = xt + (size_t)n * XT_NSTRIDE + (size_t)y0 * XT_ROWSTRIDE;
    {
        const int8_t* gsrc = xbase + lane * 16;
        const uint32_t lds0 = (uint32_t)(uintptr_t)Xraw;
        for (int j = wid; j < 33; j += 4)    // 33 chunks of 1024 B
            glds16(gsrc + j * 1024,
                   __builtin_amdgcn_readfirstlane(lds0 + j * 1024));
        asm volatile("s_waitcnt vmcnt(0)" ::: "memory");
        __syncthreads();
    }

    const int row    = lane & 15;           // A: co-row   B: m-col
    const int quad   = lane >> 4;           // k quad (16 bytes)
    const int co_off = (wid >> 1) * 64;
    const int m_off  = (wid & 1) * 64;      // selects output row y0 / y0+1

    const int8_t* wbase = wp + (size_t)(co0 + co_off + row) * CIN + quad * 16;
    const int8_t* Xw    = Xraw + (wid & 1) * XT_ROWSTRIDE;

    v4i acc[4][4] = {};                     // [co-subtile][m-subtile]

#pragma unroll
    for (int tap = 0; tap < 9; ++tap) {
        const int ky = tap / 3, kx = tap % 3;
        const int8_t* wt = wbase + tap * WP_TAPSTRIDE;
        const int8_t* xl = Xw + ky * XT_ROWSTRIDE;
        const int pxr = row + kx;           // pixel for m=0; (px&7)=(pxr&7)
#pragma unroll
        for (int half = 0; half < 2; ++half) {
            const int sw = ((half * 4 + quad) ^ (pxr & 7)) << 4;  // swizzled chunk
            v4i af[4], bf[4];
#pragma unroll
            for (int c = 0; c < 4; ++c)
                af[c] = *(const v4i*)(wt + half * 64 + c * 16 * CIN);
#pragma unroll
            for (int m = 0; m < 4; ++m)
                bf[m] = *(const v4i*)(xl + (pxr + m * 16) * CIN + sw);
#pragma unroll
            for (int c = 0; c < 4; ++c)
#pragma unroll
                for (int m = 0; m < 4; ++m)
                    acc[c][m] = __builtin_amdgcn_mfma_i32_16x16x64_i8(
                        af[c], bf[m], acc[c][m], 0, 0, 0);
        }
    }

    // Epilogue. D 16x16 layout: col = lane&15 (m), row = quad*4 + reg (co).
    const float* bco = bias + co0 + co_off;
    const float* sco = sign + co0 + co_off;
    float* outb = out + ((size_t)n * COUT + co0 + co_off) * (HH * WW)
                + y0 * WW + m_off;
#pragma unroll
    for (int c = 0; c < 4; ++c) {
#pragma unroll
        for (int r = 0; r < 4; ++r) {
            const int col_co = c * 16 + quad * 4 + r;
            const float bv = bco[col_co];
            const float sv = sco[col_co];
            float* orow = outb + (size_t)col_co * (HH * WW);
#pragma unroll
            for (int m = 0; m < 4; ++m) {
                const float yv = (float)acc[c][m][r] + bv;   // exact ints
                const bool on = (sv > 0.0f) ? (yv >= 0.0f) : (yv <= 0.0f);
                orow[m * 16 + row] = on ? 1.0f : 0.0f;
            }
        }
    }
}

// -------------------------------------------------------------------------
// Fallback (only if ws too small): naive direct conv, one thread per output.
__global__ __launch_bounds__(256) void naive_conv(
    const float* __restrict__ x, const float* __restrict__ w,
    const float* __restrict__ bias, const float* __restrict__ sign,
    float* __restrict__ out) {
    const int idx = blockIdx.x * 256 + threadIdx.x;
    const int xc = idx & 63, y = (idx >> 6) & 63, co = (idx >> 12) & 255,
              n = idx >> 20;
    float s = 0.f;
    for (int ci = 0; ci < CIN; ++ci)
        for (int ky = 0; ky < 3; ++ky) {
            const int iy = y + ky - 1;
            if (iy < 0 || iy >= HH) continue;
            for (int kx = 0; kx < 3; ++kx) {
                const int ix = xc + kx - 1;
                if (ix < 0 || ix >= WW) continue;
                s += x[((size_t)(n * CIN + ci) * HH + iy) * WW + ix] *
                     w[((size_t)(co * CIN + ci) * 3 + ky) * 3 + kx];
            }
        }
    const float yv = s + bias[co];
    out[idx] = ((sign[co] > 0.f) ? (yv >= 0.f) : (yv <= 0.f)) ? 1.0f : 0.0f;
}

// -------------------------------------------------------------------------
extern "C" void kernel_launch(void* const* d_in, const int* in_sizes, int n_in,
                              void* d_out, int out_size, void* d_ws, size_t ws_size,
                              hipStream_t stream) {
    const float* x    = (const float*)d_in[0];
    const float* w    = (const float*)d_in[1];
    const float* bias = (const float*)d_in[2];
    const float* sign = (const float*)d_in[3];
    float* out = (float*)d_out;

    const size_t need = XT_BYTES + WP_BYTES;   // ~18.1 MiB
    if (ws_size < need) {
        naive_conv<<<dim3((NIMG * COUT * HH * WW) / 256), 256, 0, stream>>>(
            x, w, bias, sign, out);
        return;
    }
    int8_t* xt = (int8_t*)d_ws;
    int8_t* wp = (int8_t*)d_ws + XT_BYTES;

    xt_prepass<<<dim3(PH, NIMG), 256, 0, stream>>>(x, xt);
    w_prepack<<<dim3((int)(WP_BYTES + 255) / 256), 256, 0, stream>>>(w, wp);
    binconv_gemm<<<dim3(NIMG * (HH / 2), COUT / 128), 256, 0, stream>>>(
        xt, wp, bias, sign, out);
}

// Round 4
// 221.104 us; speedup vs baseline: 1.2110x; 1.2110x over previous
//
#include <hip/hip_runtime.h>
#include <cstdint>

// BinConv2dEval: y = conv3x3(x,W) + bias; out = (sign*y >= 0) ? 1 : 0
// x: [32][128][64][64] fp32 in {0,1};  W: [256][128][3][3] fp32 in {-1,0,1}
// bias: [256] integer-valued fp32; sign: [256] in {-1,+1}; out fp32 NCHW.
//
// Strategy: all-integer implicit GEMM with i8 MFMA (16x16x64).
//  ws: xt = i8 NHWC zero-padded [32][66][66][128], chunk-swizzled (17.8 MB)
//      wp = i8 [tap(9)][co(256)][ci(128)], chunk-swizzled      (288 KB)
// R3: XOR-swizzle on xt chunks (LDS conflicts -> 0).
// R4: W via LDS double-buffer with async tap-ahead glds16 prefetch
//     (R2/R3's per-wave global W loads were TA/latency-bound: 16 cache
//     lines per load, unhidden; R1 A/B proved W-in-LDS is faster).
//     wp gains the same XOR chunk swizzle keyed on co&7 so the verbatim
//     DMA staging yields conflict-free af reads.

#define NIMG 32
#define CIN  128
#define HH   64
#define WW   64
#define COUT 256
#define PH   66                       // padded spatial
#define XT_ROWSTRIDE (PH * CIN)       // 8448 bytes per padded row
#define XT_NSTRIDE   (PH * PH * CIN)  // 557568 bytes per image
#define XT_BYTES     ((size_t)NIMG * XT_NSTRIDE)
#define WP_TAPSTRIDE (COUT * CIN)     // 32768
#define WP_BYTES     ((size_t)9 * WP_TAPSTRIDE)

typedef int v4i __attribute__((ext_vector_type(4)));

// -------------------------------------------------------------------------
// Prepass: x fp32 NCHW -> i8 NHWC (chunk-swizzled), zero-padded borders.
// Swizzle: 16-B chunk c of pixel px lands at position c ^ (px & 7).
__global__ __launch_bounds__(256) void xt_prepass(const float* __restrict__ x,
                                                  int8_t* __restrict__ xt) {
    const int py = blockIdx.x;   // 0..65
    const int n  = blockIdx.y;   // 0..31
    const int t  = threadIdx.x;
    int8_t* rowbase = xt + (size_t)(n * PH + py) * XT_ROWSTRIDE;

    if (py == 0 || py == PH - 1) {          // pure pad row: zeros
        int4 z = {0, 0, 0, 0};
        for (int j = t; j < XT_ROWSTRIDE / 16; j += 256)
            ((int4*)rowbase)[j] = z;
        return;
    }

    __shared__ __align__(16) int8_t Ls[64 * 144];  // [x][ci], +16B row pad
    const int y  = py - 1;
    const int xq = t & 15;                  // float4 index along x
    const float4* xf = (const float4*)x;
#pragma unroll
    for (int j = 0; j < 8; ++j) {
        const int ci = (t >> 4) + j * 16;   // 0..127
        float4 v = xf[((size_t)(n * CIN + ci) * HH + y) * 16 + xq];
        const int xv = xq * 4;
        Ls[(xv + 0) * 144 + ci] = (int8_t)v.x;
        Ls[(xv + 1) * 144 + ci] = (int8_t)v.y;
        Ls[(xv + 2) * 144 + ci] = (int8_t)v.z;
        Ls[(xv + 3) * 144 + ci] = (int8_t)v.w;
    }
    __syncthreads();
    const int4 z = {0, 0, 0, 0};
    for (int j = t; j < XT_ROWSTRIDE / 16; j += 256) {   // 528 int4 chunks
        const int px  = j >> 3;             // 0..65
        const int c   = j & 7;              // source chunk within pixel
        int4 val;
        if (px == 0 || px == PH - 1) val = z;
        else                         val = *(const int4*)&Ls[(px - 1) * 144 + c * 16];
        *(int4*)(rowbase + (size_t)px * CIN + ((c ^ (px & 7)) << 4)) = val;
    }
}

// -------------------------------------------------------------------------
// Weight prepack: OIHW fp32 -> i8 [tap][co][ci], chunk c at c ^ (co&7).
__global__ __launch_bounds__(256) void w_prepack(const float* __restrict__ w,
                                                 int8_t* __restrict__ wp) {
    const int idx = blockIdx.x * 256 + threadIdx.x;   // 0..294911
    if (idx >= (int)WP_BYTES) return;
    const int tap = idx >> 15;          // /32768
    const int rem = idx & 32767;
    const int co  = rem >> 7;
    const int ci  = rem & 127;
    const int pos = ((ci >> 4) ^ (co & 7));
    wp[tap * WP_TAPSTRIDE + co * CIN + (pos << 4) + (ci & 15)] =
        (int8_t)w[(size_t)(co * CIN + ci) * 9 + tap];
}

// -------------------------------------------------------------------------
// async global->LDS, 16B/lane. LDS dest = m0 (wave-uniform) + lane*16.
__device__ __forceinline__ void glds16(const void* g, uint32_t lds_off) {
    asm volatile("s_mov_b32 m0, %0\n"
                 "global_load_lds_dwordx4 %1, off"
                 :: "s"(lds_off), "v"(g) : "memory");
}

// -------------------------------------------------------------------------
// Main GEMM: D[co][m] = sum_taps W_tap[co][ci] * X_tap[ci][m]
// block: 128co x 128m (2 output rows x 64 cols), 4 waves, each 64co x 64m.
// X: 4 padded xt rows staged ONCE (33,792 B, swizzled, conflict-free).
// W: 16 KB/tap double-buffered in LDS; tap+1 prefetched via glds16 while
//    computing tap; ONE vmcnt(0)+barrier per tap (prefetch hides under
//    the 32-MFMA burst).
__global__ __launch_bounds__(256) void binconv_gemm(
    const int8_t* __restrict__ xt, const int8_t* __restrict__ wp,
    const float* __restrict__ bias, const float* __restrict__ sign,
    float* __restrict__ out) {

    __shared__ __align__(16) int8_t Xraw[4 * XT_ROWSTRIDE];  // 33,792 B
    __shared__ __align__(16) int8_t Wlds[2][16384];          // 32,768 B

    const int t    = threadIdx.x;
    const int wid  = t >> 6;
    const int lane = t & 63;
    const int bx   = blockIdx.x;            // 1024 m-blocks
    const int co0  = blockIdx.y * 128;      // 0 / 128
    const int n    = bx >> 5;
    const int y0   = (bx & 31) << 1;        // 2 output rows per block

    const int8_t* xbase = xt + (size_t)n * XT_NSTRIDE + (size_t)y0 * XT_ROWSTRIDE;
    const int8_t* wslice = wp + co0 * CIN;  // [tap][128 co][128] slices

    // ---- initial stage: X (33 KiB) + W tap 0 (16 KiB) ----
    {
        const uint32_t ldsX = (uint32_t)(uintptr_t)Xraw;
        const uint32_t ldsW = (uint32_t)(uintptr_t)&Wlds[0][0];
        const int8_t* gx = xbase + lane * 16;
        const int8_t* gw = wslice + lane * 16;
        for (int j = wid; j < 33; j += 4)
            glds16(gx + j * 1024, __builtin_amdgcn_readfirstlane(ldsX + j * 1024));
        for (int j = wid; j < 16; j += 4)
            glds16(gw + j * 1024, __builtin_amdgcn_readfirstlane(ldsW + j * 1024));
        asm volatile("s_waitcnt vmcnt(0)" ::: "memory");
        __syncthreads();
    }

    const int row    = lane & 15;           // A: co-row   B: m-col
    const int quad   = lane >> 4;           // k quad (16 bytes)
    const int co_off = (wid >> 1) * 64;
    const int m_off  = (wid & 1) * 64;      // selects output row y0 / y0+1

    const int8_t* Xw = Xraw + (wid & 1) * XT_ROWSTRIDE;

    v4i acc[4][4] = {};                     // [co-subtile][m-subtile]

#pragma unroll
    for (int tap = 0; tap < 9; ++tap) {
        // prefetch next tap's W tile into the other buffer (async)
        if (tap < 8) {
            const uint32_t ldsWn = (uint32_t)(uintptr_t)&Wlds[(tap + 1) & 1][0];
            const int8_t* gw = wslice + (tap + 1) * WP_TAPSTRIDE + lane * 16;
            for (int j = wid; j < 16; j += 4)
                glds16(gw + j * 1024,
                       __builtin_amdgcn_readfirstlane(ldsWn + j * 1024));
        }

        const int ky = tap / 3, kx = tap % 3;
        const int8_t* wl = &Wlds[tap & 1][0] + (co_off + row) * CIN;
        const int8_t* xl = Xw + ky * XT_ROWSTRIDE;
        const int pxr = row + kx;           // pixel for m=0; (px&7)=(pxr&7)
        const int rs  = row & 7;            // W swizzle key
#pragma unroll
        for (int half = 0; half < 2; ++half) {
            const int swX = ((half * 4 + quad) ^ (pxr & 7)) << 4;
            const int swW = ((half * 4 + quad) ^ rs) << 4;
            v4i af[4], bf[4];
#pragma unroll
            for (int c = 0; c < 4; ++c)
                af[c] = *(const v4i*)(wl + c * 16 * CIN + swW);
#pragma unroll
            for (int m = 0; m < 4; ++m)
                bf[m] = *(const v4i*)(xl + (pxr + m * 16) * CIN + swX);
#pragma unroll
            for (int c = 0; c < 4; ++c)
#pragma unroll
                for (int m = 0; m < 4; ++m)
                    acc[c][m] = __builtin_amdgcn_mfma_i32_16x16x64_i8(
                        af[c], bf[m], acc[c][m], 0, 0, 0);
        }

        if (tap < 8) {   // prefetch landed under the MFMA burst
            asm volatile("s_waitcnt vmcnt(0)" ::: "memory");
            __syncthreads();
        }
    }

    // Epilogue. D 16x16 layout: col = lane&15 (m), row = quad*4 + reg (co).
    const float* bco = bias + co0 + co_off;
    const float* sco = sign + co0 + co_off;
    float* outb = out + ((size_t)n * COUT + co0 + co_off) * (HH * WW)
                + y0 * WW + m_off;
#pragma unroll
    for (int c = 0; c < 4; ++c) {
#pragma unroll
        for (int r = 0; r < 4; ++r) {
            const int col_co = c * 16 + quad * 4 + r;
            const float bv = bco[col_co];
            const float sv = sco[col_co];
            float* orow = outb + (size_t)col_co * (HH * WW);
#pragma unroll
            for (int m = 0; m < 4; ++m) {
                const float yv = (float)acc[c][m][r] + bv;   // exact ints
                const bool on = (sv > 0.0f) ? (yv >= 0.0f) : (yv <= 0.0f);
                orow[m * 16 + row] = on ? 1.0f : 0.0f;
            }
        }
    }
}

// -------------------------------------------------------------------------
// Fallback (only if ws too small): naive direct conv, one thread per output.
__global__ __launch_bounds__(256) void naive_conv(
    const float* __restrict__ x, const float* __restrict__ w,
    const float* __restrict__ bias, const float* __restrict__ sign,
    float* __restrict__ out) {
    const int idx = blockIdx.x * 256 + threadIdx.x;
    const int xc = idx & 63, y = (idx >> 6) & 63, co = (idx >> 12) & 255,
              n = idx >> 20;
    float s = 0.f;
    for (int ci = 0; ci < CIN; ++ci)
        for (int ky = 0; ky < 3; ++ky) {
            const int iy = y + ky - 1;
            if (iy < 0 || iy >= HH) continue;
            for (int kx = 0; kx < 3; ++kx) {
                const int ix = xc + kx - 1;
                if (ix < 0 || ix >= WW) continue;
                s += x[((size_t)(n * CIN + ci) * HH + iy) * WW + ix] *
                     w[((size_t)(co * CIN + ci) * 3 + ky) * 3 + kx];
            }
        }
    const float yv = s + bias[co];
    out[idx] = ((sign[co] > 0.f) ? (yv >= 0.f) : (yv <= 0.f)) ? 1.0f : 0.0f;
}

// -------------------------------------------------------------------------
extern "C" void kernel_launch(void* const* d_in, const int* in_sizes, int n_in,
                              void* d_out, int out_size, void* d_ws, size_t ws_size,
                              hipStream_t stream) {
    const float* x    = (const float*)d_in[0];
    const float* w    = (const float*)d_in[1];
    const float* bias = (const float*)d_in[2];
    const float* sign = (const float*)d_in[3];
    float* out = (float*)d_out;

    const size_t need = XT_BYTES + WP_BYTES;   // ~18.1 MiB
    if (ws_size < need) {
        naive_conv<<<dim3((NIMG * COUT * HH * WW) / 256), 256, 0, stream>>>(
            x, w, bias, sign, out);
        return;
    }
    int8_t* xt = (int8_t*)d_ws;
    int8_t* wp = (int8_t*)d_ws + XT_BYTES;

    xt_prepass<<<dim3(PH, NIMG), 256, 0, stream>>>(x, xt);
    w_prepack<<<dim3((int)(WP_BYTES + 255) / 256), 256, 0, stream>>>(w, wp);
    binconv_gemm<<<dim3(NIMG * (HH / 2), COUT / 128), 256, 0, stream>>>(
        xt, wp, bias, sign, out);
}

// Round 5
// 219.104 us; speedup vs baseline: 1.2220x; 1.0091x over previous
//
#include <hip/hip_runtime.h>
#include <cstdint>

// BinConv2dEval: y = conv3x3(x,W) + bias; out = (sign*y >= 0) ? 1 : 0
// x: [32][128][64][64] fp32 in {0,1};  W: [256][128][3][3] fp32 in {-1,0,1}
// bias: [256] integer-valued fp32; sign: [256] in {-1,+1}; out fp32 NCHW.
//
// Strategy: all-integer implicit GEMM with i8 MFMA (16x16x64).
//  ws: xt = i8 NHWC zero-padded [32][66][66][128], chunk-swizzled (17.8 MB)
//      wq = i8 fragment-major [tap(9)][co64(4)][half(2)][c(4)][lane(64)x16B]
// R3: XOR-swizzle on xt chunks (LDS conflicts -> 0, verified).
// R5: W via fragment-major COALESCED global loads (1 KB/wave-load, L1/L2
//     hot) — no W LDS, no per-tap barriers. R4's per-tap barrier forced
//     all waves into LDS-phase/MFMA-phase lockstep at 2 blocks/CU; this
//     round the 9-tap body is one barrier-free straight line, LDS traffic
//     halves, and LDS drops to 33.8 KB (3-4 blocks/CU).

#define NIMG 32
#define CIN  128
#define HH   64
#define WW   64
#define COUT 256
#define PH   66                       // padded spatial
#define XT_ROWSTRIDE (PH * CIN)       // 8448 bytes per padded row
#define XT_NSTRIDE   (PH * PH * CIN)  // 557568 bytes per image
#define XT_BYTES     ((size_t)NIMG * XT_NSTRIDE)
#define WP_TAPSTRIDE (COUT * CIN)     // 32768
#define WP_BYTES     ((size_t)9 * WP_TAPSTRIDE)

typedef int v4i __attribute__((ext_vector_type(4)));

// -------------------------------------------------------------------------
// Prepass: x fp32 NCHW -> i8 NHWC (chunk-swizzled), zero-padded borders.
// Swizzle: 16-B chunk c of pixel px lands at position c ^ (px & 7).
__global__ __launch_bounds__(256) void xt_prepass(const float* __restrict__ x,
                                                  int8_t* __restrict__ xt) {
    const int py = blockIdx.x;   // 0..65
    const int n  = blockIdx.y;   // 0..31
    const int t  = threadIdx.x;
    int8_t* rowbase = xt + (size_t)(n * PH + py) * XT_ROWSTRIDE;

    if (py == 0 || py == PH - 1) {          // pure pad row: zeros
        int4 z = {0, 0, 0, 0};
        for (int j = t; j < XT_ROWSTRIDE / 16; j += 256)
            ((int4*)rowbase)[j] = z;
        return;
    }

    __shared__ __align__(16) int8_t Ls[64 * 144];  // [x][ci], +16B row pad
    const int y  = py - 1;
    const int xq = t & 15;                  // float4 index along x
    const float4* xf = (const float4*)x;
#pragma unroll
    for (int j = 0; j < 8; ++j) {
        const int ci = (t >> 4) + j * 16;   // 0..127
        float4 v = xf[((size_t)(n * CIN + ci) * HH + y) * 16 + xq];
        const int xv = xq * 4;
        Ls[(xv + 0) * 144 + ci] = (int8_t)v.x;
        Ls[(xv + 1) * 144 + ci] = (int8_t)v.y;
        Ls[(xv + 2) * 144 + ci] = (int8_t)v.z;
        Ls[(xv + 3) * 144 + ci] = (int8_t)v.w;
    }
    __syncthreads();
    const int4 z = {0, 0, 0, 0};
    for (int j = t; j < XT_ROWSTRIDE / 16; j += 256) {   // 528 int4 chunks
        const int px  = j >> 3;             // 0..65
        const int c   = j & 7;              // source chunk within pixel
        int4 val;
        if (px == 0 || px == PH - 1) val = z;
        else                         val = *(const int4*)&Ls[(px - 1) * 144 + c * 16];
        *(int4*)(rowbase + (size_t)px * CIN + ((c ^ (px & 7)) << 4)) = val;
    }
}

// -------------------------------------------------------------------------
// Weight prepack: OIHW fp32 -> i8 fragment-major wq.
// For (tap, co, ci): half=ci>>6, quad=(ci>>4)&3, b=ci&15,
//                    cot=co>>6, c=(co>>4)&3, row=co&15, lane=quad*16+row.
// dst = tap*32768 + cot*8192 + half*4096 + c*1024 + lane*16 + b
// => af[half][c] for a wave covering co64-tile `cot` is ONE contiguous
//    1-KB load at lane*16.
__global__ __launch_bounds__(256) void w_prepack(const float* __restrict__ w,
                                                 int8_t* __restrict__ wq) {
    const int idx = blockIdx.x * 256 + threadIdx.x;   // 0..294911
    if (idx >= (int)WP_BYTES) return;
    const int tap = idx >> 15;          // /32768
    const int rem = idx & 32767;
    const int co  = rem >> 7;
    const int ci  = rem & 127;
    const int half = ci >> 6, quad = (ci >> 4) & 3, b = ci & 15;
    const int cot = co >> 6, c = (co >> 4) & 3, row = co & 15;
    wq[tap * 32768 + cot * 8192 + half * 4096 + c * 1024
       + (quad * 16 + row) * 16 + b] =
        (int8_t)w[(size_t)(co * CIN + ci) * 9 + tap];
}

// -------------------------------------------------------------------------
// async global->LDS, 16B/lane. LDS dest = m0 (wave-uniform) + lane*16.
__device__ __forceinline__ void glds16(const void* g, uint32_t lds_off) {
    asm volatile("s_mov_b32 m0, %0\n"
                 "global_load_lds_dwordx4 %1, off"
                 :: "s"(lds_off), "v"(g) : "memory");
}

// -------------------------------------------------------------------------
// Main GEMM: D[co][m] = sum_taps W_tap[co][ci] * X_tap[ci][m]
// block: 128co x 128m (2 output rows x 64 cols), 4 waves, each 64co x 64m.
// X: 4 padded xt rows staged ONCE (33,792 B, swizzled, conflict-free).
// W: fragment-major coalesced global loads, 8 x 1KB per wave per tap.
// ZERO barriers after the initial X stage.
__global__ __launch_bounds__(256) void binconv_gemm(
    const int8_t* __restrict__ xt, const int8_t* __restrict__ wq,
    const float* __restrict__ bias, const float* __restrict__ sign,
    float* __restrict__ out) {

    __shared__ __align__(16) int8_t Xraw[4 * XT_ROWSTRIDE];  // 33,792 B

    const int t    = threadIdx.x;
    const int wid  = t >> 6;
    const int lane = t & 63;
    const int bx   = blockIdx.x;            // 1024 m-blocks
    const int co0  = blockIdx.y * 128;      // 0 / 128
    const int n    = bx >> 5;
    const int y0   = (bx & 31) << 1;        // 2 output rows per block

    // ---- stage 4 padded rows (33 KiB) verbatim, once ----
    const int8_t* xbase = xt + (size_t)n * XT_NSTRIDE + (size_t)y0 * XT_ROWSTRIDE;
    {
        const int8_t* gsrc = xbase + lane * 16;
        const uint32_t lds0 = (uint32_t)(uintptr_t)Xraw;
        for (int j = wid; j < 33; j += 4)    // 33 chunks of 1024 B
            glds16(gsrc + j * 1024,
                   __builtin_amdgcn_readfirstlane(lds0 + j * 1024));
        asm volatile("s_waitcnt vmcnt(0)" ::: "memory");
        __syncthreads();
    }

    const int row    = lane & 15;           // A: co-row   B: m-col
    const int quad   = lane >> 4;           // k quad (16 bytes)
    const int co_off = (wid >> 1) * 64;
    const int m_off  = (wid & 1) * 64;      // selects output row y0 / y0+1

    const int8_t* Xw  = Xraw + (wid & 1) * XT_ROWSTRIDE;
    // wave's fragment-major W base: co64-tile index + per-lane 16 B
    const int8_t* wqb = wq + ((co0 + co_off) >> 6) * 8192 + lane * 16;

    v4i acc[4][4] = {};                     // [co-subtile][m-subtile]

#pragma unroll
    for (int tap = 0; tap < 9; ++tap) {
        const int ky = tap / 3, kx = tap % 3;
        const int8_t* wqt = wqb + tap * 32768;
        const int8_t* xl  = Xw + ky * XT_ROWSTRIDE;
        const int pxr = row + kx;           // pixel for m=0; (px&7)=(pxr&7)

        v4i af[2][4];                       // all 8 A-fragments of this tap
#pragma unroll
        for (int h = 0; h < 2; ++h)
#pragma unroll
            for (int c = 0; c < 4; ++c)
                af[h][c] = *(const v4i*)(wqt + h * 4096 + c * 1024);

#pragma unroll
        for (int h = 0; h < 2; ++h) {
            const int swX = ((h * 4 + quad) ^ (pxr & 7)) << 4;
            v4i bf[4];
#pragma unroll
            for (int m = 0; m < 4; ++m)
                bf[m] = *(const v4i*)(xl + (pxr + m * 16) * CIN + swX);
#pragma unroll
            for (int c = 0; c < 4; ++c)
#pragma unroll
                for (int m = 0; m < 4; ++m)
                    acc[c][m] = __builtin_amdgcn_mfma_i32_16x16x64_i8(
                        af[h][c], bf[m], acc[c][m], 0, 0, 0);
        }
    }

    // Epilogue. D 16x16 layout: col = lane&15 (m), row = quad*4 + reg (co).
    const float* bco = bias + co0 + co_off;
    const float* sco = sign + co0 + co_off;
    float* outb = out + ((size_t)n * COUT + co0 + co_off) * (HH * WW)
                + y0 * WW + m_off;
#pragma unroll
    for (int c = 0; c < 4; ++c) {
#pragma unroll
        for (int r = 0; r < 4; ++r) {
            const int col_co = c * 16 + quad * 4 + r;
            const float bv = bco[col_co];
            const float sv = sco[col_co];
            float* orow = outb + (size_t)col_co * (HH * WW);
#pragma unroll
            for (int m = 0; m < 4; ++m) {
                const float yv = (float)acc[c][m][r] + bv;   // exact ints
                const bool on = (sv > 0.0f) ? (yv >= 0.0f) : (yv <= 0.0f);
                orow[m * 16 + row] = on ? 1.0f : 0.0f;
            }
        }
    }
}

// -------------------------------------------------------------------------
// Fallback (only if ws too small): naive direct conv, one thread per output.
__global__ __launch_bounds__(256) void naive_conv(
    const float* __restrict__ x, const float* __restrict__ w,
    const float* __restrict__ bias, const float* __restrict__ sign,
    float* __restrict__ out) {
    const int idx = blockIdx.x * 256 + threadIdx.x;
    const int xc = idx & 63, y = (idx >> 6) & 63, co = (idx >> 12) & 255,
              n = idx >> 20;
    float s = 0.f;
    for (int ci = 0; ci < CIN; ++ci)
        for (int ky = 0; ky < 3; ++ky) {
            const int iy = y + ky - 1;
            if (iy < 0 || iy >= HH) continue;
            for (int kx = 0; kx < 3; ++kx) {
                const int ix = xc + kx - 1;
                if (ix < 0 || ix >= WW) continue;
                s += x[((size_t)(n * CIN + ci) * HH + iy) * WW + ix] *
                     w[((size_t)(co * CIN + ci) * 3 + ky) * 3 + kx];
            }
        }
    const float yv = s + bias[co];
    out[idx] = ((sign[co] > 0.f) ? (yv >= 0.f) : (yv <= 0.f)) ? 1.0f : 0.0f;
}

// -------------------------------------------------------------------------
extern "C" void kernel_launch(void* const* d_in, const int* in_sizes, int n_in,
                              void* d_out, int out_size, void* d_ws, size_t ws_size,
                              hipStream_t stream) {
    const float* x    = (const float*)d_in[0];
    const float* w    = (const float*)d_in[1];
    const float* bias = (const float*)d_in[2];
    const float* sign = (const float*)d_in[3];
    float* out = (float*)d_out;

    const size_t need = XT_BYTES + WP_BYTES;   // ~18.1 MiB
    if (ws_size < need) {
        naive_conv<<<dim3((NIMG * COUT * HH * WW) / 256), 256, 0, stream>>>(
            x, w, bias, sign, out);
        return;
    }
    int8_t* xt = (int8_t*)d_ws;
    int8_t* wq = (int8_t*)d_ws + XT_BYTES;

    xt_prepass<<<dim3(PH, NIMG), 256, 0, stream>>>(x, xt);
    w_prepack<<<dim3((int)(WP_BYTES + 255) / 256), 256, 0, stream>>>(w, wq);
    binconv_gemm<<<dim3(NIMG * (HH / 2), COUT / 128), 256, 0, stream>>>(
        xt, wq, bias, sign, out);
}